// Round 5
// baseline (246.057 us; speedup 1.0000x reference)
//
#include <hip/hip_runtime.h>
#include <cstdint>
#include <cstddef>

#define TOKENS 8192
#define IN_F   4096
#define OUT_F  4096
#define QMAXF  127.0f
#define EPSF   1e-8f

typedef int i32x4  __attribute__((ext_vector_type(4)));
typedef int i32x16 __attribute__((ext_vector_type(16)));

#define BKB 64                    // K-bytes per K-step
#define NT  (IN_F / BKB)          // 64 K-steps
// per buffer: A 16 KB (256 rows x 64 B) + B 8 KB (128 rows x 64 B)
#define ABYTES 16384
#define BUFB   24576
// 2 buffers = 48 KB static LDS -> 2 blocks/CU co-resident

__device__ __forceinline__ void gload16(const void* g, void* l) {
    __builtin_amdgcn_global_load_lds(
        (const __attribute__((address_space(1))) void*)g,
        (__attribute__((address_space(3))) void*)l,
        16, 0, 0);
}

__device__ __forceinline__ int quant1(float v, float inv) {
    int q = (int)rintf(v * inv);
    q = q > 127 ? 127 : q;
    q = q < -127 ? -127 : q;
    return q;
}

__device__ __forceinline__ unsigned int pack4i(int a, int b, int c, int d) {
    return (unsigned int)(a & 255) | ((unsigned int)(b & 255) << 8) |
           ((unsigned int)(c & 255) << 16) | ((unsigned int)(d & 255) << 24);
}

// One block per token: absmax reduce + int8 quantize.
__global__ __launch_bounds__(256) void quant_x_kernel(const float* __restrict__ x,
                                                      signed char* __restrict__ xq,
                                                      float* __restrict__ xscale) {
    const int t   = blockIdx.x;
    const int tid = threadIdx.x;
    const float* xr = x + (size_t)t * IN_F + tid * 16;

    float4 v[4];
    float am = 0.0f;
#pragma unroll
    for (int i = 0; i < 4; ++i) {
        v[i] = ((const float4*)xr)[i];
        am = fmaxf(am, fmaxf(fmaxf(fabsf(v[i].x), fabsf(v[i].y)),
                             fmaxf(fabsf(v[i].z), fabsf(v[i].w))));
    }
#pragma unroll
    for (int off = 32; off >= 1; off >>= 1)
        am = fmaxf(am, __shfl_xor(am, off));

    __shared__ float wmax[4];
    const int wid = tid >> 6, lane = tid & 63;
    if (lane == 0) wmax[wid] = am;
    __syncthreads();
    am = fmaxf(fmaxf(wmax[0], wmax[1]), fmaxf(wmax[2], wmax[3]));

    const float s   = fmaxf(am, EPSF) / QMAXF;
    const float inv = QMAXF / fmaxf(am, EPSF);
    if (tid == 0) xscale[t] = s;

    unsigned int w[4];
#pragma unroll
    for (int i = 0; i < 4; ++i) {
        w[i] = pack4i(quant1(v[i].x, inv), quant1(v[i].y, inv),
                      quant1(v[i].z, inv), quant1(v[i].w, inv));
    }
    *(uint4*)(xq + (size_t)t * IN_F + tid * 16) = make_uint4(w[0], w[1], w[2], w[3]);
}

// Repack int32-held int8 weights into dense int8.
__global__ __launch_bounds__(256) void pack_w_kernel(const int* __restrict__ w,
                                                     signed char* __restrict__ wq) {
    const size_t idx = (size_t)blockIdx.x * 256 + threadIdx.x;
    const int4* src = (const int4*)w + idx * 4;
    unsigned int o[4];
#pragma unroll
    for (int i = 0; i < 4; ++i) {
        int4 u = src[i];
        o[i] = pack4i(u.x, u.y, u.z, u.w);
    }
    ((uint4*)wq)[idx] = make_uint4(o[0], o[1], o[2], o[3]);
}

// 256x128 tile, 256 threads (4 waves 2x2), wave tile 128x64,
// mfma_i32_32x32x32_i8, 2-buffer double-buffer, stage-first + vmcnt(0)
// + 1 barrier per K-step. TWO blocks co-resident per CU (48 KB LDS,
// ~200 VGPR) -> independent barrier domains overlap LDS and MFMA pipes.
// LDS layout per 16-row window (1024 B): slot = g*256 + (row&15)*16
// (g = 16B k-granule) -> every b128 fragment read is 4x contiguous
// 256 B chunks: conflict-free (verified 0 conflicts in R3/R4).
__global__ __launch_bounds__(256, 2) void gemm_kernel(const signed char* __restrict__ xq,
                                                      const signed char* __restrict__ wq,
                                                      const float* __restrict__ xscale,
                                                      const float* __restrict__ wscale,
                                                      const float* __restrict__ bias,
                                                      float* __restrict__ out) {
    __shared__ __align__(16) char lds[2 * BUFB];

    const int tid  = threadIdx.x;
    const int wid  = tid >> 6;
    const int lane = tid & 63;
    const int wr   = wid >> 1;   // 0..1
    const int wc   = wid & 1;    // 0..1

    // XCD-aware bijective swizzle (1024 blocks, 1024 % 8 == 0)
    const int bid = blockIdx.x;
    const int swz = (bid & 7) * 128 + (bid >> 3);
    const int bm0 = (swz >> 5) * 256;   // 32 m-tiles
    const int bn0 = (swz & 31) * 128;   // 32 n-tiles

    // ---- staging map: call c covers 64 rows x 64 B (4 KB) ----
    const int srow = ((tid >> 6) << 4) + (tid & 15);   // 0..63 row within call
    const int scol = ((tid >> 4) & 3) * 16;            // k-granule byte
    const signed char* pA = xq + (size_t)(bm0 + srow) * IN_F + scol;
    const signed char* pB = wq + (size_t)(bn0 + srow) * IN_F + scol;
    const int ldst = tid * 16;

    // ---- fragment read offsets ----
    const int l31 = lane & 31, hi = lane >> 5;
    int a_off[4][2], b_off[2][2];
#pragma unroll
    for (int m = 0; m < 4; ++m) {
        const int win = wr * 8 + m * 2 + (l31 >> 4);
#pragma unroll
        for (int ks = 0; ks < 2; ++ks)
            a_off[m][ks] = win * 1024 + (ks * 2 + hi) * 256 + (l31 & 15) * 16;
    }
#pragma unroll
    for (int n = 0; n < 2; ++n) {
        const int win = wc * 4 + n * 2 + (l31 >> 4);
#pragma unroll
        for (int ks = 0; ks < 2; ++ks)
            b_off[n][ks] = ABYTES + win * 1024 + (ks * 2 + hi) * 256 + (l31 & 15) * 16;
    }

    i32x16 acc[4][2];
#pragma unroll
    for (int m = 0; m < 4; ++m)
#pragma unroll
        for (int n = 0; n < 2; ++n)
#pragma unroll
            for (int r = 0; r < 16; ++r) acc[m][n][r] = 0;

    // ---- prologue: stage K-step 0 into buf 0 ----
    {
        char* S = lds;
#pragma unroll
        for (int c = 0; c < 4; ++c)
            gload16(pA + (size_t)c * 64 * IN_F, S + c * 4096 + ldst);
#pragma unroll
        for (int c = 0; c < 2; ++c)
            gload16(pB + (size_t)c * 64 * IN_F, S + ABYTES + c * 4096 + ldst);
    }
    asm volatile("s_waitcnt vmcnt(0)" ::: "memory");
    __builtin_amdgcn_s_barrier();

    for (int t = 0; t < NT; ++t) {
        const char* Ab = lds + (t & 1) * BUFB;

        // ---- stage next K-step first (earliest safe point: its buffer's
        // ---- last reads finished before the barrier that ended tile t-1)
        if (t + 1 < NT) {
            char* S = lds + ((t + 1) & 1) * BUFB;
            const int ko = (t + 1) * BKB;
#pragma unroll
            for (int c = 0; c < 4; ++c)
                gload16(pA + (size_t)c * 64 * IN_F + ko, S + c * 4096 + ldst);
#pragma unroll
            for (int c = 0; c < 2; ++c)
                gload16(pB + (size_t)c * 64 * IN_F + ko, S + ABYTES + c * 4096 + ldst);
        }

        // ---- fragment reads (B first so first MFMA's operands land early)
        i32x4 b[2][2], a[4][2];
#pragma unroll
        for (int n = 0; n < 2; ++n)
#pragma unroll
            for (int ks = 0; ks < 2; ++ks)
                b[n][ks] = *(const i32x4*)(Ab + b_off[n][ks]);
#pragma unroll
        for (int m = 0; m < 4; ++m)
#pragma unroll
            for (int ks = 0; ks < 2; ++ks)
                a[m][ks] = *(const i32x4*)(Ab + a_off[m][ks]);

        __builtin_amdgcn_s_setprio(1);
#pragma unroll
        for (int m = 0; m < 4; ++m)
#pragma unroll
            for (int n = 0; n < 2; ++n)
#pragma unroll
                for (int ks = 0; ks < 2; ++ks)
                    acc[m][n] = __builtin_amdgcn_mfma_i32_32x32x32_i8(a[m][ks], b[n][ks], acc[m][n], 0, 0, 0);
        __builtin_amdgcn_s_setprio(0);

        // ---- tile boundary: next-step staging must have landed ----
        asm volatile("s_waitcnt vmcnt(0)" ::: "memory");
        __builtin_amdgcn_s_barrier();
    }

    // ---- epilogue: dequant + bias ----
    // C/D 32x32 layout: col = lane&31, row = (reg&3) + 8*(reg>>2) + 4*(lane>>5)
#pragma unroll
    for (int m = 0; m < 4; ++m) {
        const int rbase = bm0 + wr * 128 + m * 32 + 4 * hi;
        float xsv[16];
#pragma unroll
        for (int r = 0; r < 16; ++r)
            xsv[r] = xscale[rbase + (r & 3) + 8 * (r >> 2)];
#pragma unroll
        for (int n = 0; n < 2; ++n) {
            const int col = bn0 + wc * 64 + n * 32 + l31;
            const float wsc = wscale[col];
            const float bv  = bias[col];
#pragma unroll
            for (int r = 0; r < 16; ++r) {
                const int row = rbase + (r & 3) + 8 * (r >> 2);
                out[(size_t)row * OUT_F + col] = (float)acc[m][n][r] * xsv[r] * wsc + bv;
            }
        }
    }
}

extern "C" void kernel_launch(void* const* d_in, const int* in_sizes, int n_in,
                              void* d_out, int out_size, void* d_ws, size_t ws_size,
                              hipStream_t stream) {
    const float* x      = (const float*)d_in[0];
    const int*   w      = (const int*)d_in[1];     // int8 weights held as int32
    const float* wscale = (const float*)d_in[2];
    const float* bias   = (const float*)d_in[3];
    float* out = (float*)d_out;

    char* ws = (char*)d_ws;
    signed char* xq  = (signed char*)ws;                                   // 33.5 MB
    signed char* wq8 = (signed char*)(ws + (size_t)TOKENS * IN_F);         // 16.8 MB
    float* xscale    = (float*)(ws + (size_t)TOKENS * IN_F + (size_t)OUT_F * IN_F);

    quant_x_kernel<<<TOKENS, 256, 0, stream>>>(x, xq, xscale);
    pack_w_kernel<<<(OUT_F * (IN_F / 16)) / 256, 256, 0, stream>>>(w, wq8);
    gemm_kernel<<<(TOKENS / 256) * (OUT_F / 128), 256, 0, stream>>>(
        xq, wq8, xscale, wscale, bias, out);
}